// Round 7
// baseline (175.772 us; speedup 1.0000x reference)
//
#include <hip/hip_runtime.h>
#include <hip/hip_bf16.h>

// NPZD plankton ODE: B*WK = 106496 independent trajectories, 56 Euler steps.
//
// Sampled hours are exactly h=3j (168w+3s = 3(56w+s)) -> load gf/gm rows
// with perfectly-coalesced float4 loads (each line fetched once), compact
// every-3rd word into LDS, integrate 1 trajectory/lane from LDS.
// R6 proved this beats the stride-3 gather wall (kernel 64 -> <43 us).
//
// R7: split each batch across 2 blocks (grid 4096). Half-row staging is
// exactly float4-aligned (4368 h-words = 1092 float4). LDS 25 -> 12.6 KB
// and staged VGPRs 72 -> 40, so more resident blocks/CU and a finer
// execution tail (R6: 8 blocks/CU needed, ~6 resident -> 2-of-8 tail).
// Floor: 143.5 MB reads + 13.6 MB writes at ~6.6 TB/s (fill-measured) ~ 24 us.

typedef float f32x4 __attribute__((ext_vector_type(4)));

#define NPZD_B 2048
#define NPZD_WK 52
#define NPZD_HRS 8760
#define NPZD_HWK 26            // weeks per block (half batch)
#define NPZD_NF4H 1092         // float4 per half-row range (4368 words)
#define NPZD_WSTRIDE 60        // padded words per week (16B-aligned)
#define NPZD_LDSW (NPZD_HWK * NPZD_WSTRIDE + 16)   // 1576 words

__global__ __launch_bounds__(256) void npzd_kernel(
    const float* __restrict__ X_in,     // (B, WK, 5, 1)
    const float* __restrict__ gf,       // (B, HRS)
    const float* __restrict__ gm,       // (B, HRS)
    const float* __restrict__ params,   // (B, 10)
    const float* __restrict__ dt_ptr,   // scalar
    float* __restrict__ out)            // (B, WK, 4, 8)
{
    __shared__ __align__(16) float lds_f[NPZD_LDSW];
    __shared__ __align__(16) float lds_m[NPZD_LDSW];

    const int blk = blockIdx.x;
    const int b   = blk >> 1;          // batch
    const int q   = blk & 1;           // half: weeks [26q, 26q+26)
    const int tid = threadIdx.x;

    const f32x4* __restrict__ gf4 = (const f32x4*)(gf + (size_t)b * NPZD_HRS);
    const f32x4* __restrict__ gm4 = (const f32x4*)(gm + (size_t)b * NPZD_HRS);

    // ---- Phase 1a: stage this block's half-row, fully coalesced ----
    const int k0   = q * NPZD_NF4H;
    const int kmax = k0 + NPZD_NF4H - 1;
    f32x4 fv[5], mv[5];
    int kk[5];
    #pragma unroll
    for (int i = 0; i < 5; ++i) {
        int k = k0 + i * 256 + tid;
        if (k > kmax) k = kmax;        // clamp: dup load+dup write, benign
        kk[i] = k;
        fv[i] = __builtin_nontemporal_load(gf4 + k);
        mv[i] = __builtin_nontemporal_load(gm4 + k);
    }

    // ---- Phase 1b: compact every-3rd word into LDS ----
    // float4 k covers h = 4k..4k+3; h%3==0 at e0=(3-k%3)%3 (and e0+3 if k%3==0).
    // j = h/3; global dest p = j + 4*(j/56) (= 60w + s); local = p - 1560q.
    // Magic div j/56 = (j*9363)>>19 exact for j <= 2919.
    const int pbase = 1560 * q;
    #pragma unroll
    for (int i = 0; i < 5; ++i) {
        const int k = kk[i];
        const float fe[4] = {fv[i].x, fv[i].y, fv[i].z, fv[i].w};
        const float me[4] = {mv[i].x, mv[i].y, mv[i].z, mv[i].w};
        const int rm = k % 3;
        const int e0 = (rm == 0) ? 0 : (3 - rm);
        const int j0 = (4 * k + e0) / 3;
        const int p0 = j0 + 4 * ((j0 * 9363) >> 19) - pbase;
        lds_f[p0] = fe[e0];
        lds_m[p0] = me[e0];
        if (rm == 0) {                 // second multiple of 3 in this float4
            const int j1 = j0 + 1;
            const int p1 = j1 + 4 * ((j1 * 9363) >> 19) - pbase;
            lds_f[p1] = fe[3];
            lds_m[p1] = me[3];
        }
    }
    __syncthreads();

    // ---- Phase 2: lanes 0..25 integrate one trajectory each ----
    if (tid >= NPZD_HWK) return;
    const int w = q * NPZD_HWK + tid;  // global week

    const float dt = dt_ptr[0];        // 0.125

    const float* xb = X_in + ((size_t)b * NPZD_WK + w) * 5;
    float N = xb[1], P = xb[2], Z = xb[3], D = xb[4];

    const float* pp = params + (size_t)b * 10;   // block-uniform -> s_load
    const float chi   = pp[0];
    const float rho2  = pp[1] * 2.0f;
    const float gam1  = pp[2] * 0.1f;
    const float lam05 = pp[3] * 0.05f;
    const float eps1  = pp[4] * 0.1f;
    const float alp3  = pp[5] * 0.3f;
    const float bet6  = pp[6] * 0.6f;
    const float eta15 = pp[7] * 0.15f;
    const float phi4  = pp[8] * 0.4f;
    const float zet1  = pp[9] * 0.1f;
    const float rem   = 1.0f - alp3 - bet6;

    float oN[8], oP[8], oZ[8], oD[8];
    oN[0] = N; oP[0] = P; oZ[0] = Z; oD[0] = D;

    const float* lf = lds_f + tid * NPZD_WSTRIDE;
    const float* lm = lds_m + tid * NPZD_WSTRIDE;

    #pragma unroll
    for (int g = 0; g < 14; ++g) {
        // one aligned ds_read_b128 per array per 4 steps
        const f32x4 f4 = *(const f32x4*)(lf + 4 * g);
        const f32x4 m4 = *(const f32x4*)(lm + 4 * g);
        const float fs[4] = {f4.x, f4.y, f4.z, f4.w};
        const float ms[4] = {m4.x, m4.y, m4.z, m4.w};
        #pragma unroll
        for (int qq = 0; qq < 4; ++qq) {
            const float ft = fs[qq], mt = ms[qq];
            const float Pc = fmaxf(0.01f, P);
            const float Zc = fmaxf(0.01f, Z);
            const float gN = N * __builtin_amdgcn_rcpf(chi + N);
            const float zg = rho2 * (1.0f - __expf(-lam05 * Pc)) * Zc;
            const float up = gN * ft * Pc;
            const float Nn = N + dt * (-up + alp3 * zg + eps1 * P + gam1 * Z + phi4 * D + mt * (8.0f - N));
            const float Pn = P + dt * (up - zg - eps1 * P - eta15 * P - mt * P);
            const float Zn = Z + dt * (bet6 * zg - gam1 * Z - mt * Z);
            const float Dn = D + dt * (eta15 * P + rem * zg - phi4 * D - zet1 * D - mt * D);
            N = Nn; P = Pn; Z = Zn; D = Dn;
        }
        if (g & 1) {   // after steps 7,15,...,55
            const int c = (g >> 1) + 1;
            oN[c] = N; oP[c] = P; oZ[c] = Z; oD[c] = D;
        }
    }

    // Output: (b, w, state, 8) -> 32 contiguous floats per trajectory.
    // R1-R6 measured WRITE_SIZE == output bytes exactly -> no RMW penalty.
    f32x4* o4 = (f32x4*)(out + ((size_t)b * NPZD_WK + w) * 32);
    o4[0] = (f32x4){oN[0], oN[1], oN[2], oN[3]};
    o4[1] = (f32x4){oN[4], oN[5], oN[6], oN[7]};
    o4[2] = (f32x4){oP[0], oP[1], oP[2], oP[3]};
    o4[3] = (f32x4){oP[4], oP[5], oP[6], oP[7]};
    o4[4] = (f32x4){oZ[0], oZ[1], oZ[2], oZ[3]};
    o4[5] = (f32x4){oZ[4], oZ[5], oZ[6], oZ[7]};
    o4[6] = (f32x4){oD[0], oD[1], oD[2], oD[3]};
    o4[7] = (f32x4){oD[4], oD[5], oD[6], oD[7]};
}

extern "C" void kernel_launch(void* const* d_in, const int* in_sizes, int n_in,
                              void* d_out, int out_size, void* d_ws, size_t ws_size,
                              hipStream_t stream) {
    const float* X_in   = (const float*)d_in[0];
    const float* gf     = (const float*)d_in[1];
    const float* gm     = (const float*)d_in[2];
    const float* params = (const float*)d_in[3];
    const float* dt_ptr = (const float*)d_in[4];
    float* out = (float*)d_out;

    npzd_kernel<<<NPZD_B * 2, 256, 0, stream>>>(X_in, gf, gm, params, dt_ptr, out);
}